// Round 19
// baseline (146.088 us; speedup 1.0000x reference)
//
#include <hip/hip_runtime.h>
#include <hip/hip_bf16.h>
#include <math.h>

#define DD 64
#define LOG2E 1.44269504f
#define LN2 0.69314718f
#define NEG_L2E (-1.44269504f)

__device__ __forceinline__ float frcp(float x) { return __builtin_amdgcn_rcpf(x); }
__device__ __forceinline__ float fsig(float x) { return frcp(1.0f + __expf(-x)); }
__device__ __forceinline__ float fsilu(float x) { return x * fsig(x); }

// Fused setup: [0,N/4) coord | [N/4,N/2) sdf | then keysT | then B | then scale
__global__ __launch_bounds__(256) void k_setup(
    const float* __restrict__ coords, const float* __restrict__ W1,
    const float* __restrict__ b1, const float* __restrict__ W2,
    const float* __restrict__ b2, const float* __restrict__ keys,
    const float* __restrict__ rpos, const float* __restrict__ rrad,
    const float* __restrict__ mem, const float* __restrict__ Wg1,
    const float* __restrict__ Wu1, const float* __restrict__ Wg2,
    float* __restrict__ qe, float* __restrict__ keysT,
    float* __restrict__ sg_out, float* __restrict__ BgT,
    float* __restrict__ Bu, float* __restrict__ wg1r_n,
    float* __restrict__ wu1r_n, float* __restrict__ w2n, int N, int M, int R) {
  int bx = blockIdx.x;
  int NB4 = N / 4;
  if (bx < NB4) {
    // coord_proj: 4 n per block
    int sub = threadIdx.x >> 6, k = threadIdx.x & 63;
    int n = bx * 4 + sub;
    __shared__ float h[4][DD];
    float px = coords[n * 3 + 0], py = coords[n * 3 + 1], pz = coords[n * 3 + 2];
    float t = px * W1[k] + py * W1[DD + k] + pz * W1[2 * DD + k] + b1[k];
    h[sub][k] = fsilu(t);
    __syncthreads();
    float q = b2[k];
#pragma unroll 8
    for (int j = 0; j < DD; j++) q += h[sub][j] * W2[j * DD + k];
    qe[(size_t)n * DD + k] = q;
  } else if (bx < 2 * NB4) {
    // sdf: one wave per n
    int wv = threadIdx.x >> 6, ln = threadIdx.x & 63;
    int n = (bx - NB4) * 4 + wv;
    float px = coords[n * 3], py = coords[n * 3 + 1], pz = coords[n * 3 + 2];
    float mn = 1e30f;
    for (int r = ln; r < R; r += 64) {
      float dx = px - rpos[r * 3], dy = py - rpos[r * 3 + 1],
            dz = pz - rpos[r * 3 + 2];
      float d = sqrtf(dx * dx + dy * dy + dz * dz) - rrad[r];
      mn = fminf(mn, d);
    }
    mn = fminf(mn, __shfl_xor(mn, 32, 64));
    mn = fminf(mn, __shfl_xor(mn, 16, 64));
    mn = fminf(mn, __shfl_xor(mn, 8, 64));
    mn = fminf(mn, __shfl_xor(mn, 4, 64));
    mn = fminf(mn, __shfl_xor(mn, 2, 64));
    mn = fminf(mn, __shfl_xor(mn, 1, 64));
    if (ln == 0) sg_out[n] = fsig(4.0f * mn);
  } else if (bx < 2 * NB4 + DD) {
    // keysT[j][m] = keys[m][j]
    int j = bx - 2 * NB4;
    int t = threadIdx.x;
    keysT[j * M + t] = keys[t * DD + j];
  } else if (bx < 2 * NB4 + DD + M) {
    // initial BgT/Bu (negated log2 domain)
    int m = bx - (2 * NB4 + DD);
    int t = threadIdx.x;
    __shared__ float row[DD];
    if (t < DD) row[t] = mem[m * DD + t];
    __syncthreads();
    if (t < 128) {
      int k = t & 63;
      const float* W = (t < DD) ? Wg1 : Wu1;
      float b = 0.f;
#pragma unroll 8
      for (int j = 0; j < DD; j++) b += row[j] * W[(DD + j) * DD + k];
      b *= NEG_L2E;
      if (t < DD) BgT[k * M + m] = b;
      else Bu[m * DD + k] = b;
    }
  } else {
    // prescaled weight rows
    int k = threadIdx.x;
    if (k < DD) {
      wg1r_n[k] = Wg1[128 * DD + k] * NEG_L2E;
      wu1r_n[k] = Wu1[128 * DD + k] * NEG_L2E;
      w2n[k] = -Wg2[k] * LN2;
    }
  }
}

// 8 n's per block; XCD-aligned with k_write consumers. A-proj outputs in
// negated-log2 domain. No max-sub softmax (logits bounded). final==0: skip
// pure-output stores. Shared streams (keysT, mem, W) amortized over 8 n.
__global__ __launch_bounds__(256) void k_attn(
    const float* __restrict__ qe_in, const float* __restrict__ keysT,
    const float* __restrict__ mem, const float* __restrict__ sg,
    const float* __restrict__ Wg1, const float* __restrict__ bg1,
    const float* __restrict__ Wu1, const float* __restrict__ bu1,
    float* __restrict__ rw_out, float* __restrict__ rwT,
    float* __restrict__ mc_out, float* __restrict__ qe_io,
    float* __restrict__ AgT4, float* __restrict__ Au, int N, int M, int NCH2,
    int final_step) {
  int bx = blockIdx.x;
  int c = bx % NCH2;        // XCD = bx%8 = c%8
  int j2 = bx / NCH2;       // 0..15
  int n0 = c * 128 + j2 * 8;
  int t = threadIdx.x;  // t == m, M == 256
  int wv = t >> 6, ln = t & 63;
  __shared__ __align__(16) float rws[8][256];
  __shared__ __align__(16) float mcs[8][DD];
  __shared__ float red2[8][4];
  __shared__ float part[8][4][DD];
  float lg[8] = {0.f, 0.f, 0.f, 0.f, 0.f, 0.f, 0.f, 0.f};
#pragma unroll 8
  for (int j = 0; j < DD; j++) {
    float kv = keysT[j * M + t];
#pragma unroll
    for (int q = 0; q < 8; q++)
      lg[q] += qe_in[(size_t)(n0 + q) * DD + j] * kv;  // uniform -> s_load
  }
  float e[8];
#pragma unroll
  for (int q = 0; q < 8; q++) {
    // logits bounded: no max-subtraction needed
    float ee = __expf(lg[q] * 0.125f);
    e[q] = ee;
    float sm = ee;
    sm += __shfl_xor(sm, 32, 64);
    sm += __shfl_xor(sm, 16, 64);
    sm += __shfl_xor(sm, 8, 64);
    sm += __shfl_xor(sm, 4, 64);
    sm += __shfl_xor(sm, 2, 64);
    sm += __shfl_xor(sm, 1, 64);
    if (ln == 0) red2[q][wv] = sm;
  }
  __syncthreads();
  float rv8[8];
#pragma unroll
  for (int q = 0; q < 8; q++) {
    float tot = red2[q][0] + red2[q][1] + red2[q][2] + red2[q][3];
    float rv = e[q] * frcp(tot);
    if (final_step) rw_out[(size_t)(n0 + q) * M + t] = rv;
    rws[q][t] = rv;
    rv8[q] = rv;
  }
  *reinterpret_cast<float4*>(&rwT[(size_t)t * N + n0]) =
      make_float4(rv8[0], rv8[1], rv8[2], rv8[3]);
  *reinterpret_cast<float4*>(&rwT[(size_t)t * N + n0 + 4]) =
      make_float4(rv8[4], rv8[5], rv8[6], rv8[7]);
  __syncthreads();
  float acc[8] = {0.f, 0.f, 0.f, 0.f, 0.f, 0.f, 0.f, 0.f};
#pragma unroll
  for (int mm4 = 0; mm4 < 16; mm4++) {
    int mbase = wv * 64 + mm4 * 4;
    float m0v = mem[(size_t)(mbase + 0) * DD + ln];
    float m1v = mem[(size_t)(mbase + 1) * DD + ln];
    float m2v = mem[(size_t)(mbase + 2) * DD + ln];
    float m3v = mem[(size_t)(mbase + 3) * DD + ln];
#pragma unroll
    for (int q = 0; q < 8; q++) {
      const float4 r = *reinterpret_cast<const float4*>(&rws[q][mbase]);
      acc[q] += r.x * m0v + r.y * m1v + r.z * m2v + r.w * m3v;
    }
  }
#pragma unroll
  for (int q = 0; q < 8; q++) part[q][wv][ln] = acc[q];
  __syncthreads();
#pragma unroll
  for (int qq = 0; qq < 2; qq++) {
    int q = wv + qq * 4;
    float mc = part[q][0][ln] + part[q][1][ln] + part[q][2][ln] + part[q][3][ln];
    if (final_step) mc_out[(size_t)(n0 + q) * DD + ln] = mc;
    qe_io[(size_t)(n0 + q) * DD + ln] =
        qe_in[(size_t)(n0 + q) * DD + ln] + 0.5f * mc;
    mcs[q][ln] = mc;
  }
  __syncthreads();
  // A-proj: waves 0,1 = gate (q 0-3 / 4-7), waves 2,3 = update (q 0-3 / 4-7)
  {
    const float* W = (wv < 2) ? Wg1 : Wu1;
    const float* bb = (wv < 2) ? bg1 : bu1;
    int q0 = (wv & 1) * 4;
    int k = ln;
    float w129 = W[129 * DD + k];
    float bbk = bb[k];
    float a[4];
#pragma unroll
    for (int i = 0; i < 4; i++) a[i] = bbk + sg[n0 + q0 + i] * w129;
#pragma unroll
    for (int j4 = 0; j4 < 16; j4++) {
      float w0 = W[(size_t)(j4 * 4 + 0) * DD + k];
      float w1 = W[(size_t)(j4 * 4 + 1) * DD + k];
      float w2v = W[(size_t)(j4 * 4 + 2) * DD + k];
      float w3 = W[(size_t)(j4 * 4 + 3) * DD + k];
#pragma unroll
      for (int i = 0; i < 4; i++) {
        const float4 mv = *reinterpret_cast<const float4*>(&mcs[q0 + i][j4 * 4]);
        a[i] += mv.x * w0 + mv.y * w1 + mv.z * w2v + mv.w * w3;
      }
    }
#pragma unroll
    for (int i = 0; i < 4; i++) {
      float av = a[i] * NEG_L2E;
      if (wv < 2)
        AgT4[((size_t)(k >> 2) * N + n0 + q0 + i) * 4 + (k & 3)] = av;
      else
        Au[(size_t)(n0 + q0 + i) * DD + k] = av;
    }
  }
}

// Main pair loop (R13/R17 structure, best measured): 128 thr = 2 waves over ONE
// 64-n chunk; wave 0 = gate path, wave 1 = delta path (no LDS, no barriers).
// 4 m's per block; frcp silu; negated log2 domain.
__global__ __launch_bounds__(128) void k_write(
    const float* __restrict__ rwT, const float* __restrict__ AgT4,
    const float* __restrict__ Au, const float* __restrict__ BgT,
    const float* __restrict__ Bu, const float* __restrict__ wg1r_n,
    const float* __restrict__ wu1r_n, const float* __restrict__ w2n,
    const float* __restrict__ bg2, float* __restrict__ gate_part,
    float* __restrict__ su_part, int N, int M, int NCH2) {
  int bx = blockIdx.x;
  int c128 = bx % NCH2;
  int rest = bx / NCH2;
  int half = rest & 1;
  int m0 = (rest >> 1) * 4;
  int NCH4 = NCH2 * 2;
  int c64 = c128 * 2 + half;
  int wave = threadIdx.x >> 6, lane = threadIdx.x & 63;
  int n0 = __builtin_amdgcn_readfirstlane(c64 * 64);

  if (wave == 0) {
    // ---- gate path: lane = n offset, loop k (pipelined ag4) ----
    float rwl[4];
#pragma unroll
    for (int mi = 0; mi < 4; mi++)
      rwl[mi] = rwT[(size_t)(m0 + mi) * N + n0 + lane];
    float gacc[4] = {0.f, 0.f, 0.f, 0.f};
    const float* agp = &AgT4[(size_t)(n0 + lane) * 4];
    float4 ag_cur = *reinterpret_cast<const float4*>(agp);
#pragma unroll
    for (int k4 = 0; k4 < 16; k4++) {
      float4 ag_next = (k4 < 15)
          ? *reinterpret_cast<const float4*>(agp + (size_t)(k4 + 1) * N * 4)
          : ag_cur;
      float agv[4] = {ag_cur.x, ag_cur.y, ag_cur.z, ag_cur.w};
#pragma unroll
      for (int kk = 0; kk < 4; kk++) {
        int k = k4 * 4 + kk;
        const float4 bg4 =
            *reinterpret_cast<const float4*>(&BgT[k * M + m0]);  // s_load
        float bgv[4] = {bg4.x, bg4.y, bg4.z, bg4.w};
        float wr = wg1r_n[k];
        float w2 = w2n[k];
#pragma unroll
        for (int mi = 0; mi < 4; mi++) {
          float tp = fmaf(rwl[mi], wr, agv[kk] + bgv[mi]);  // -t*log2e
          float ee = __builtin_amdgcn_exp2f(tp);
          gacc[mi] = fmaf(tp * w2, frcp(1.0f + ee), gacc[mi]);  // silu*Wg2
        }
      }
      ag_cur = ag_next;
    }
    float bg2v = bg2[0];
    float g[4];
#pragma unroll
    for (int mi = 0; mi < 4; mi++) {
      float gg = fsig(gacc[mi] + bg2v);
      gg += __shfl_xor(gg, 32, 64);
      gg += __shfl_xor(gg, 16, 64);
      gg += __shfl_xor(gg, 8, 64);
      gg += __shfl_xor(gg, 4, 64);
      gg += __shfl_xor(gg, 2, 64);
      gg += __shfl_xor(gg, 1, 64);
      g[mi] = gg;
    }
    if (lane == 0) {
#pragma unroll
      for (int mi = 0; mi < 4; mi++)
        gate_part[(m0 + mi) * NCH4 + c64] = g[mi];
    }
  } else {
    // ---- delta path: lane = k, loop n (pipelined au) ----
    float bu[4];
#pragma unroll
    for (int mi = 0; mi < 4; mi++) bu[mi] = Bu[(size_t)(m0 + mi) * DD + lane];
    float wu = wu1r_n[lane];
    float su[4] = {0.f, 0.f, 0.f, 0.f};
    const float* Aup = Au + (size_t)n0 * DD + lane;
    const float* r0p = rwT + (size_t)(m0 + 0) * N + n0;  // contiguous s_loads
    const float* r1p = rwT + (size_t)(m0 + 1) * N + n0;
    const float* r2p = rwT + (size_t)(m0 + 2) * N + n0;
    const float* r3p = rwT + (size_t)(m0 + 3) * N + n0;
    float au_cur = Aup[0];
#pragma unroll 8
    for (int i = 0; i < 64; i++) {
      float au_next = (i < 63) ? Aup[(size_t)(i + 1) * DD] : au_cur;
      float rvs[4] = {r0p[i], r1p[i], r2p[i], r3p[i]};
#pragma unroll
      for (int mi = 0; mi < 4; mi++) {
        float tp = fmaf(rvs[mi], wu, au_cur + bu[mi]);     // -t*log2e
        float ee = __builtin_amdgcn_exp2f(tp);
        su[mi] = fmaf(tp, frcp(1.0f + ee), su[mi]);        // sum(t'*sig)
      }
      au_cur = au_next;
    }
#pragma unroll
    for (int mi = 0; mi < 4; mi++)
      su_part[((size_t)(m0 + mi) * NCH4 + c64) * DD + lane] = su[mi] * (-LN2);
  }
}

// per-m reduce over NCH4=64 chunks, PARALLELIZED: 256 thr; 4 waves split the
// su gather; gate gather is lane-parallel + butterfly.
__global__ __launch_bounds__(256) void k_reduce_b(
    const float* __restrict__ gate_part, const float* __restrict__ su_part,
    const float* __restrict__ Wu2, const float* __restrict__ bu2,
    const float* __restrict__ mem_in, const float* __restrict__ Wg1,
    const float* __restrict__ Wu1, float* __restrict__ mem_out,
    float* __restrict__ gate_out, float* __restrict__ BgT,
    float* __restrict__ Bu, int N, int M, int NCH4) {
  int m = blockIdx.x;
  int t = threadIdx.x;
  int w = t >> 6, k = t & 63;
  __shared__ float su_s4[4][DD];
  __shared__ float su_s[DD];
  __shared__ float row[DD];
  __shared__ float gmean;
  float invN = frcp((float)N);  // N pow2 -> exact
  // su gather: wave w covers chunks c = w, w+4, ...
  float s = 0.f;
  for (int c = w; c < NCH4; c += 4)
    s += su_part[((size_t)m * NCH4 + c) * DD + k];
  su_s4[w][k] = s;
  // gate gather: wave 0, lane = chunk (NCH4 == 64)
  if (w == 0) {
    float g = gate_part[m * NCH4 + k];
    g += __shfl_xor(g, 32, 64);
    g += __shfl_xor(g, 16, 64);
    g += __shfl_xor(g, 8, 64);
    g += __shfl_xor(g, 4, 64);
    g += __shfl_xor(g, 2, 64);
    g += __shfl_xor(g, 1, 64);
    if (k == 0) gmean = g * invN;
  }
  __syncthreads();
  if (t < DD) {
    su_s[k] = (su_s4[0][k] + su_s4[1][k] + su_s4[2][k] + su_s4[3][k]) * invN;
  }
  __syncthreads();
  if (t < DD) {
    float delta = bu2[k];
#pragma unroll 8
    for (int j = 0; j < DD; j++) delta += su_s[j] * Wu2[j * DD + k];
    float v = mem_in[m * DD + k] + gmean * delta;
    mem_out[m * DD + k] = v;
    row[k] = v;
    if (k == 0) gate_out[m] = gmean;
  }
  __syncthreads();
  if (t < 128) {
    const float* W = (t < DD) ? Wg1 : Wu1;
    float b = 0.f;
#pragma unroll 8
    for (int j = 0; j < DD; j++) b += row[j] * W[(DD + j) * DD + k];
    b *= NEG_L2E;
    if (t < DD) BgT[k * M + m] = b;
    else Bu[m * DD + k] = b;
  }
}

extern "C" void kernel_launch(void* const* d_in, const int* in_sizes, int n_in,
                              void* d_out, int out_size, void* d_ws, size_t ws_size,
                              hipStream_t stream) {
  const float* coords = (const float*)d_in[0];
  const float* memory_slots = (const float*)d_in[1];
  const float* anchor_keys = (const float*)d_in[2];
  const float* rpos = (const float*)d_in[3];
  const float* rrad = (const float*)d_in[4];
  const float* W1 = (const float*)d_in[5];
  const float* b1 = (const float*)d_in[6];
  const float* W2 = (const float*)d_in[7];
  const float* b2 = (const float*)d_in[8];
  const float* Wg1 = (const float*)d_in[9];
  const float* bg1 = (const float*)d_in[10];
  const float* Wg2 = (const float*)d_in[11];
  const float* bg2 = (const float*)d_in[12];
  const float* Wu1 = (const float*)d_in[13];
  const float* bu1 = (const float*)d_in[14];
  const float* Wu2 = (const float*)d_in[15];
  const float* bu2 = (const float*)d_in[16];

  const int N = in_sizes[0] / 3;   // 4096
  const int M = in_sizes[1] / DD;  // 256
  const int R = in_sizes[4];       // 512
  const int NCH2 = N / 128;        // 32
  const int NCH4 = N / 64;         // 64

  // d_out layout: mc[N*D] | rw[N*M] | gate[M] | sg[N] | mem[M*D]
  float* out = (float*)d_out;
  float* out_mc = out;
  float* out_rw = out_mc + (size_t)N * DD;
  float* out_gate = out_rw + (size_t)N * M;
  float* out_sg = out_gate + M;
  float* out_mem = out_sg + N;

  // workspace layout (~11.3 MB)
  float* ws = (float*)d_ws;
  float* qe = ws;        ws += (size_t)N * DD;
  float* AgT4 = ws;      ws += (size_t)N * DD;
  float* Au = ws;        ws += (size_t)N * DD;
  float* rwT = ws;       ws += (size_t)M * N;
  float* keysT = ws;     ws += (size_t)DD * M;
  float* BgT = ws;       ws += (size_t)DD * M;
  float* Bu = ws;        ws += (size_t)M * DD;
  float* wg1r_n = ws;    ws += DD;
  float* wu1r_n = ws;    ws += DD;
  float* w2n = ws;       ws += DD;
  float* gate_part = ws; ws += (size_t)M * NCH4;
  float* su_part = ws;   ws += (size_t)M * NCH4 * DD;

  int setup_blocks = (N / 4) * 2 + DD + M + 1;  // coord + sdf + prep + b + scale
  k_setup<<<setup_blocks, 256, 0, stream>>>(
      coords, W1, b1, W2, b2, anchor_keys, rpos, rrad, memory_slots, Wg1, Wu1,
      Wg2, qe, keysT, out_sg, BgT, Bu, wg1r_n, wu1r_n, w2n, N, M, R);

  const float* mem_cur = memory_slots;
  for (int step = 0; step < 2; step++) {
    k_attn<<<N / 8, 256, 0, stream>>>(qe, keysT, mem_cur, out_sg, Wg1, bg1, Wu1,
                                      bu1, out_rw, rwT, out_mc, qe, AgT4, Au,
                                      N, M, NCH2, step == 1 ? 1 : 0);
    k_write<<<(M / 4) * 2 * NCH2, 128, 0, stream>>>(
        rwT, AgT4, Au, BgT, Bu, wg1r_n, wu1r_n, w2n, bg2, gate_part, su_part,
        N, M, NCH2);
    k_reduce_b<<<M, 256, 0, stream>>>(gate_part, su_part, Wu2, bu2, mem_cur,
                                      Wg1, Wu1, out_mem, out_gate, BgT, Bu,
                                      N, M, NCH4);
    mem_cur = out_mem;
  }
}

// Round 20
// 124.037 us; speedup vs baseline: 1.1778x; 1.1778x over previous
//
#include <hip/hip_runtime.h>
#include <hip/hip_bf16.h>
#include <math.h>

#define DD 64
#define LOG2E 1.44269504f
#define LN2 0.69314718f
#define NEG_L2E (-1.44269504f)

__device__ __forceinline__ float frcp(float x) { return __builtin_amdgcn_rcpf(x); }
__device__ __forceinline__ float fsig(float x) { return frcp(1.0f + __expf(-x)); }
__device__ __forceinline__ float fsilu(float x) { return x * fsig(x); }

// Fused setup: [0,N/4) coord | [N/4,N/2) sdf | then keysT | then B | then scale
__global__ __launch_bounds__(256) void k_setup(
    const float* __restrict__ coords, const float* __restrict__ W1,
    const float* __restrict__ b1, const float* __restrict__ W2,
    const float* __restrict__ b2, const float* __restrict__ keys,
    const float* __restrict__ rpos, const float* __restrict__ rrad,
    const float* __restrict__ mem, const float* __restrict__ Wg1,
    const float* __restrict__ Wu1, const float* __restrict__ Wg2,
    float* __restrict__ qe, float* __restrict__ keysT,
    float* __restrict__ sg_out, float* __restrict__ BgT,
    float* __restrict__ Bu, float* __restrict__ wg1r_n,
    float* __restrict__ wu1r_n, float* __restrict__ w2n, int N, int M, int R) {
  int bx = blockIdx.x;
  int NB4 = N / 4;
  if (bx < NB4) {
    // coord_proj: 4 n per block
    int sub = threadIdx.x >> 6, k = threadIdx.x & 63;
    int n = bx * 4 + sub;
    __shared__ float h[4][DD];
    float px = coords[n * 3 + 0], py = coords[n * 3 + 1], pz = coords[n * 3 + 2];
    float t = px * W1[k] + py * W1[DD + k] + pz * W1[2 * DD + k] + b1[k];
    h[sub][k] = fsilu(t);
    __syncthreads();
    float q = b2[k];
#pragma unroll 8
    for (int j = 0; j < DD; j++) q += h[sub][j] * W2[j * DD + k];
    qe[(size_t)n * DD + k] = q;
  } else if (bx < 2 * NB4) {
    // sdf: one wave per n
    int wv = threadIdx.x >> 6, ln = threadIdx.x & 63;
    int n = (bx - NB4) * 4 + wv;
    float px = coords[n * 3], py = coords[n * 3 + 1], pz = coords[n * 3 + 2];
    float mn = 1e30f;
    for (int r = ln; r < R; r += 64) {
      float dx = px - rpos[r * 3], dy = py - rpos[r * 3 + 1],
            dz = pz - rpos[r * 3 + 2];
      float d = sqrtf(dx * dx + dy * dy + dz * dz) - rrad[r];
      mn = fminf(mn, d);
    }
    mn = fminf(mn, __shfl_xor(mn, 32, 64));
    mn = fminf(mn, __shfl_xor(mn, 16, 64));
    mn = fminf(mn, __shfl_xor(mn, 8, 64));
    mn = fminf(mn, __shfl_xor(mn, 4, 64));
    mn = fminf(mn, __shfl_xor(mn, 2, 64));
    mn = fminf(mn, __shfl_xor(mn, 1, 64));
    if (ln == 0) sg_out[n] = fsig(4.0f * mn);
  } else if (bx < 2 * NB4 + DD) {
    // keysT[j][m] = keys[m][j]
    int j = bx - 2 * NB4;
    int t = threadIdx.x;
    keysT[j * M + t] = keys[t * DD + j];
  } else if (bx < 2 * NB4 + DD + M) {
    // initial BgT/Bu (negated log2 domain)
    int m = bx - (2 * NB4 + DD);
    int t = threadIdx.x;
    __shared__ float row[DD];
    if (t < DD) row[t] = mem[m * DD + t];
    __syncthreads();
    if (t < 128) {
      int k = t & 63;
      const float* W = (t < DD) ? Wg1 : Wu1;
      float b = 0.f;
#pragma unroll 8
      for (int j = 0; j < DD; j++) b += row[j] * W[(DD + j) * DD + k];
      b *= NEG_L2E;
      if (t < DD) BgT[k * M + m] = b;
      else Bu[m * DD + k] = b;
    }
  } else {
    // prescaled weight rows
    int k = threadIdx.x;
    if (k < DD) {
      wg1r_n[k] = Wg1[128 * DD + k] * NEG_L2E;
      wu1r_n[k] = Wu1[128 * DD + k] * NEG_L2E;
      w2n[k] = -Wg2[k] * LN2;
    }
  }
}

// 4 n's per block; XCD-aligned with k_write consumers. A-proj outputs in
// negated-log2 domain (x NEG_L2E). No max-sub softmax (logits bounded).
// final==0: skip pure-output stores (rw_out, mc_out).
__global__ __launch_bounds__(256) void k_attn(
    const float* __restrict__ qe_in, const float* __restrict__ keysT,
    const float* __restrict__ mem, const float* __restrict__ sg,
    const float* __restrict__ Wg1, const float* __restrict__ bg1,
    const float* __restrict__ Wu1, const float* __restrict__ bu1,
    float* __restrict__ rw_out, float* __restrict__ rwT,
    float* __restrict__ mc_out, float* __restrict__ qe_io,
    float* __restrict__ AgT4, float* __restrict__ Au, int N, int M, int NCH2,
    int final_step) {
  int bx = blockIdx.x;
  int c = bx % NCH2;        // XCD = bx%8 = c%8
  int j2 = bx / NCH2;       // 0..31
  int n0 = c * 128 + j2 * 4;
  int t = threadIdx.x;  // t == m, M == 256
  int wv = t >> 6, ln = t & 63;
  __shared__ __align__(16) float rws[4][256];
  __shared__ __align__(16) float mcs[4][DD];
  __shared__ float red2[4][4];
  __shared__ float part[4][4][DD];
  float lg[4] = {0.f, 0.f, 0.f, 0.f};
#pragma unroll 8
  for (int j = 0; j < DD; j++) {
    float kv = keysT[j * M + t];
    lg[0] += qe_in[(size_t)(n0 + 0) * DD + j] * kv;  // uniform -> s_load
    lg[1] += qe_in[(size_t)(n0 + 1) * DD + j] * kv;
    lg[2] += qe_in[(size_t)(n0 + 2) * DD + j] * kv;
    lg[3] += qe_in[(size_t)(n0 + 3) * DD + j] * kv;
  }
  float e[4];
#pragma unroll
  for (int q = 0; q < 4; q++) {
    // logits bounded (|logit| < ~10): no max-subtraction needed
    float ee = __expf(lg[q] * 0.125f);
    e[q] = ee;
    float sm = ee;
    sm += __shfl_xor(sm, 32, 64);
    sm += __shfl_xor(sm, 16, 64);
    sm += __shfl_xor(sm, 8, 64);
    sm += __shfl_xor(sm, 4, 64);
    sm += __shfl_xor(sm, 2, 64);
    sm += __shfl_xor(sm, 1, 64);
    if (ln == 0) red2[q][wv] = sm;
  }
  __syncthreads();
  float rv4[4];
#pragma unroll
  for (int q = 0; q < 4; q++) {
    float tot = red2[q][0] + red2[q][1] + red2[q][2] + red2[q][3];
    float rv = e[q] * frcp(tot);
    if (final_step) rw_out[(size_t)(n0 + q) * M + t] = rv;
    rws[q][t] = rv;
    rv4[q] = rv;
  }
  *reinterpret_cast<float4*>(&rwT[(size_t)t * N + n0]) =
      make_float4(rv4[0], rv4[1], rv4[2], rv4[3]);
  __syncthreads();
  float acc[4] = {0.f, 0.f, 0.f, 0.f};
#pragma unroll
  for (int mm4 = 0; mm4 < 16; mm4++) {
    int mbase = wv * 64 + mm4 * 4;
    const float4 r0 = *reinterpret_cast<const float4*>(&rws[0][mbase]);
    const float4 r1 = *reinterpret_cast<const float4*>(&rws[1][mbase]);
    const float4 r2 = *reinterpret_cast<const float4*>(&rws[2][mbase]);
    const float4 r3 = *reinterpret_cast<const float4*>(&rws[3][mbase]);
    float m0v = mem[(size_t)(mbase + 0) * DD + ln];
    float m1v = mem[(size_t)(mbase + 1) * DD + ln];
    float m2v = mem[(size_t)(mbase + 2) * DD + ln];
    float m3v = mem[(size_t)(mbase + 3) * DD + ln];
    acc[0] += r0.x * m0v + r0.y * m1v + r0.z * m2v + r0.w * m3v;
    acc[1] += r1.x * m0v + r1.y * m1v + r1.z * m2v + r1.w * m3v;
    acc[2] += r2.x * m0v + r2.y * m1v + r2.z * m2v + r2.w * m3v;
    acc[3] += r3.x * m0v + r3.y * m1v + r3.z * m2v + r3.w * m3v;
  }
#pragma unroll
  for (int q = 0; q < 4; q++) part[q][wv][ln] = acc[q];
  __syncthreads();
  {
    int q = wv;
    float mc = part[q][0][ln] + part[q][1][ln] + part[q][2][ln] + part[q][3][ln];
    if (final_step) mc_out[(size_t)(n0 + q) * DD + ln] = mc;
    qe_io[(size_t)(n0 + q) * DD + ln] =
        qe_in[(size_t)(n0 + q) * DD + ln] + 0.5f * mc;
    mcs[q][ln] = mc;
  }
  __syncthreads();
  {
    const float* W = (wv < 2) ? Wg1 : Wu1;
    const float* bb = (wv < 2) ? bg1 : bu1;
    int qa = (wv & 1) * 2, qb = qa + 1;
    int k = ln;
    float w129 = W[129 * DD + k];
    float bbk = bb[k];
    float a0 = bbk + sg[n0 + qa] * w129;
    float a1 = bbk + sg[n0 + qb] * w129;
#pragma unroll
    for (int j4 = 0; j4 < 16; j4++) {
      const float4 ma = *reinterpret_cast<const float4*>(&mcs[qa][j4 * 4]);
      const float4 mb = *reinterpret_cast<const float4*>(&mcs[qb][j4 * 4]);
      float w0 = W[(size_t)(j4 * 4 + 0) * DD + k];
      float w1 = W[(size_t)(j4 * 4 + 1) * DD + k];
      float w2v = W[(size_t)(j4 * 4 + 2) * DD + k];
      float w3 = W[(size_t)(j4 * 4 + 3) * DD + k];
      a0 += ma.x * w0 + ma.y * w1 + ma.z * w2v + ma.w * w3;
      a1 += mb.x * w0 + mb.y * w1 + mb.z * w2v + mb.w * w3;
    }
    a0 *= NEG_L2E;
    a1 *= NEG_L2E;
    if (wv < 2) {
      AgT4[((size_t)(k >> 2) * N + n0 + qa) * 4 + (k & 3)] = a0;
      AgT4[((size_t)(k >> 2) * N + n0 + qb) * 4 + (k & 3)] = a1;
    } else {
      Au[(size_t)(n0 + qa) * DD + k] = a0;
      Au[(size_t)(n0 + qb) * DD + k] = a1;
    }
  }
}

// Main pair loop (R13/R17 structure, best measured): 128 thr = 2 waves over ONE
// 64-n chunk; wave 0 = gate path, wave 1 = delta path (no LDS, no barriers).
// 4 m's per block; frcp silu; negated log2 domain.
__global__ __launch_bounds__(128) void k_write(
    const float* __restrict__ rwT, const float* __restrict__ AgT4,
    const float* __restrict__ Au, const float* __restrict__ BgT,
    const float* __restrict__ Bu, const float* __restrict__ wg1r_n,
    const float* __restrict__ wu1r_n, const float* __restrict__ w2n,
    const float* __restrict__ bg2, float* __restrict__ gate_part,
    float* __restrict__ su_part, int N, int M, int NCH2) {
  int bx = blockIdx.x;
  int c128 = bx % NCH2;
  int rest = bx / NCH2;
  int half = rest & 1;
  int m0 = (rest >> 1) * 4;
  int NCH4 = NCH2 * 2;
  int c64 = c128 * 2 + half;
  int wave = threadIdx.x >> 6, lane = threadIdx.x & 63;
  int n0 = __builtin_amdgcn_readfirstlane(c64 * 64);

  if (wave == 0) {
    // ---- gate path: lane = n offset, loop k (pipelined ag4) ----
    float rwl[4];
#pragma unroll
    for (int mi = 0; mi < 4; mi++)
      rwl[mi] = rwT[(size_t)(m0 + mi) * N + n0 + lane];
    float gacc[4] = {0.f, 0.f, 0.f, 0.f};
    const float* agp = &AgT4[(size_t)(n0 + lane) * 4];
    float4 ag_cur = *reinterpret_cast<const float4*>(agp);
#pragma unroll
    for (int k4 = 0; k4 < 16; k4++) {
      float4 ag_next = (k4 < 15)
          ? *reinterpret_cast<const float4*>(agp + (size_t)(k4 + 1) * N * 4)
          : ag_cur;
      float agv[4] = {ag_cur.x, ag_cur.y, ag_cur.z, ag_cur.w};
#pragma unroll
      for (int kk = 0; kk < 4; kk++) {
        int k = k4 * 4 + kk;
        const float4 bg4 =
            *reinterpret_cast<const float4*>(&BgT[k * M + m0]);  // s_load
        float bgv[4] = {bg4.x, bg4.y, bg4.z, bg4.w};
        float wr = wg1r_n[k];
        float w2 = w2n[k];
#pragma unroll
        for (int mi = 0; mi < 4; mi++) {
          float tp = fmaf(rwl[mi], wr, agv[kk] + bgv[mi]);  // -t*log2e
          float ee = __builtin_amdgcn_exp2f(tp);
          gacc[mi] = fmaf(tp * w2, frcp(1.0f + ee), gacc[mi]);  // silu*Wg2
        }
      }
      ag_cur = ag_next;
    }
    float bg2v = bg2[0];
    float g[4];
#pragma unroll
    for (int mi = 0; mi < 4; mi++) {
      float gg = fsig(gacc[mi] + bg2v);
      gg += __shfl_xor(gg, 32, 64);
      gg += __shfl_xor(gg, 16, 64);
      gg += __shfl_xor(gg, 8, 64);
      gg += __shfl_xor(gg, 4, 64);
      gg += __shfl_xor(gg, 2, 64);
      gg += __shfl_xor(gg, 1, 64);
      g[mi] = gg;
    }
    if (lane == 0) {
#pragma unroll
      for (int mi = 0; mi < 4; mi++)
        gate_part[(m0 + mi) * NCH4 + c64] = g[mi];
    }
  } else {
    // ---- delta path: lane = k, loop n (pipelined au) ----
    float bu[4];
#pragma unroll
    for (int mi = 0; mi < 4; mi++) bu[mi] = Bu[(size_t)(m0 + mi) * DD + lane];
    float wu = wu1r_n[lane];
    float su[4] = {0.f, 0.f, 0.f, 0.f};
    const float* Aup = Au + (size_t)n0 * DD + lane;
    const float* r0p = rwT + (size_t)(m0 + 0) * N + n0;  // contiguous s_loads
    const float* r1p = rwT + (size_t)(m0 + 1) * N + n0;
    const float* r2p = rwT + (size_t)(m0 + 2) * N + n0;
    const float* r3p = rwT + (size_t)(m0 + 3) * N + n0;
    float au_cur = Aup[0];
#pragma unroll 8
    for (int i = 0; i < 64; i++) {
      float au_next = (i < 63) ? Aup[(size_t)(i + 1) * DD] : au_cur;
      float rvs[4] = {r0p[i], r1p[i], r2p[i], r3p[i]};
#pragma unroll
      for (int mi = 0; mi < 4; mi++) {
        float tp = fmaf(rvs[mi], wu, au_cur + bu[mi]);     // -t*log2e
        float ee = __builtin_amdgcn_exp2f(tp);
        su[mi] = fmaf(tp, frcp(1.0f + ee), su[mi]);        // sum(t'*sig)
      }
      au_cur = au_next;
    }
#pragma unroll
    for (int mi = 0; mi < 4; mi++)
      su_part[((size_t)(m0 + mi) * NCH4 + c64) * DD + lane] = su[mi] * (-LN2);
  }
}

// per-m reduce over NCH4=64 chunks, PARALLELIZED: 256 thr; 4 waves split the
// su gather; gate gather is lane-parallel + butterfly.
__global__ __launch_bounds__(256) void k_reduce_b(
    const float* __restrict__ gate_part, const float* __restrict__ su_part,
    const float* __restrict__ Wu2, const float* __restrict__ bu2,
    const float* __restrict__ mem_in, const float* __restrict__ Wg1,
    const float* __restrict__ Wu1, float* __restrict__ mem_out,
    float* __restrict__ gate_out, float* __restrict__ BgT,
    float* __restrict__ Bu, int N, int M, int NCH4) {
  int m = blockIdx.x;
  int t = threadIdx.x;
  int w = t >> 6, k = t & 63;
  __shared__ float su_s4[4][DD];
  __shared__ float su_s[DD];
  __shared__ float row[DD];
  __shared__ float gmean;
  float invN = frcp((float)N);  // N pow2 -> exact
  // su gather: wave w covers chunks c = w, w+4, ...
  float s = 0.f;
  for (int c = w; c < NCH4; c += 4)
    s += su_part[((size_t)m * NCH4 + c) * DD + k];
  su_s4[w][k] = s;
  // gate gather: wave 0, lane = chunk (NCH4 == 64)
  if (w == 0) {
    float g = gate_part[m * NCH4 + k];
    g += __shfl_xor(g, 32, 64);
    g += __shfl_xor(g, 16, 64);
    g += __shfl_xor(g, 8, 64);
    g += __shfl_xor(g, 4, 64);
    g += __shfl_xor(g, 2, 64);
    g += __shfl_xor(g, 1, 64);
    if (k == 0) gmean = g * invN;
  }
  __syncthreads();
  if (t < DD) {
    su_s[k] = (su_s4[0][k] + su_s4[1][k] + su_s4[2][k] + su_s4[3][k]) * invN;
  }
  __syncthreads();
  if (t < DD) {
    float delta = bu2[k];
#pragma unroll 8
    for (int j = 0; j < DD; j++) delta += su_s[j] * Wu2[j * DD + k];
    float v = mem_in[m * DD + k] + gmean * delta;
    mem_out[m * DD + k] = v;
    row[k] = v;
    if (k == 0) gate_out[m] = gmean;
  }
  __syncthreads();
  if (t < 128) {
    const float* W = (t < DD) ? Wg1 : Wu1;
    float b = 0.f;
#pragma unroll 8
    for (int j = 0; j < DD; j++) b += row[j] * W[(DD + j) * DD + k];
    b *= NEG_L2E;
    if (t < DD) BgT[k * M + m] = b;
    else Bu[m * DD + k] = b;
  }
}

extern "C" void kernel_launch(void* const* d_in, const int* in_sizes, int n_in,
                              void* d_out, int out_size, void* d_ws, size_t ws_size,
                              hipStream_t stream) {
  const float* coords = (const float*)d_in[0];
  const float* memory_slots = (const float*)d_in[1];
  const float* anchor_keys = (const float*)d_in[2];
  const float* rpos = (const float*)d_in[3];
  const float* rrad = (const float*)d_in[4];
  const float* W1 = (const float*)d_in[5];
  const float* b1 = (const float*)d_in[6];
  const float* W2 = (const float*)d_in[7];
  const float* b2 = (const float*)d_in[8];
  const float* Wg1 = (const float*)d_in[9];
  const float* bg1 = (const float*)d_in[10];
  const float* Wg2 = (const float*)d_in[11];
  const float* bg2 = (const float*)d_in[12];
  const float* Wu1 = (const float*)d_in[13];
  const float* bu1 = (const float*)d_in[14];
  const float* Wu2 = (const float*)d_in[15];
  const float* bu2 = (const float*)d_in[16];

  const int N = in_sizes[0] / 3;   // 4096
  const int M = in_sizes[1] / DD;  // 256
  const int R = in_sizes[4];       // 512
  const int NCH2 = N / 128;        // 32
  const int NCH4 = N / 64;         // 64

  // d_out layout: mc[N*D] | rw[N*M] | gate[M] | sg[N] | mem[M*D]
  float* out = (float*)d_out;
  float* out_mc = out;
  float* out_rw = out_mc + (size_t)N * DD;
  float* out_gate = out_rw + (size_t)N * M;
  float* out_sg = out_gate + M;
  float* out_mem = out_sg + N;

  // workspace layout (~11.3 MB)
  float* ws = (float*)d_ws;
  float* qe = ws;        ws += (size_t)N * DD;
  float* AgT4 = ws;      ws += (size_t)N * DD;
  float* Au = ws;        ws += (size_t)N * DD;
  float* rwT = ws;       ws += (size_t)M * N;
  float* keysT = ws;     ws += (size_t)DD * M;
  float* BgT = ws;       ws += (size_t)DD * M;
  float* Bu = ws;        ws += (size_t)M * DD;
  float* wg1r_n = ws;    ws += DD;
  float* wu1r_n = ws;    ws += DD;
  float* w2n = ws;       ws += DD;
  float* gate_part = ws; ws += (size_t)M * NCH4;
  float* su_part = ws;   ws += (size_t)M * NCH4 * DD;

  int setup_blocks = (N / 4) * 2 + DD + M + 1;  // coord + sdf + prep + b + scale
  k_setup<<<setup_blocks, 256, 0, stream>>>(
      coords, W1, b1, W2, b2, anchor_keys, rpos, rrad, memory_slots, Wg1, Wu1,
      Wg2, qe, keysT, out_sg, BgT, Bu, wg1r_n, wu1r_n, w2n, N, M, R);

  const float* mem_cur = memory_slots;
  for (int step = 0; step < 2; step++) {
    k_attn<<<N / 4, 256, 0, stream>>>(qe, keysT, mem_cur, out_sg, Wg1, bg1, Wu1,
                                      bu1, out_rw, rwT, out_mc, qe, AgT4, Au,
                                      N, M, NCH2, step == 1 ? 1 : 0);
    k_write<<<(M / 4) * 2 * NCH2, 128, 0, stream>>>(
        rwT, AgT4, Au, BgT, Bu, wg1r_n, wu1r_n, w2n, bg2, gate_part, su_part,
        N, M, NCH2);
    k_reduce_b<<<M, 256, 0, stream>>>(gate_part, su_part, Wu2, bu2, mem_cur,
                                      Wg1, Wu1, out_mem, out_gate, BgT, Bu,
                                      N, M, NCH4);
    mem_cur = out_mem;
  }
}

// Round 21
// 118.376 us; speedup vs baseline: 1.2341x; 1.0478x over previous
//
#include <hip/hip_runtime.h>
#include <hip/hip_bf16.h>
#include <math.h>

#define DD 64
#define LOG2E 1.44269504f
#define LN2 0.69314718f
#define NEG_L2E (-1.44269504f)

typedef float v2f __attribute__((ext_vector_type(2)));

__device__ __forceinline__ float frcp(float x) { return __builtin_amdgcn_rcpf(x); }
__device__ __forceinline__ float fsig(float x) { return frcp(1.0f + __expf(-x)); }
__device__ __forceinline__ float fsilu(float x) { return x * fsig(x); }
// paired sigmoid in negated-log2 domain: sig_i = 1/(1+2^{t_i}), one rcp for two
__device__ __forceinline__ v2f sig_pair(v2f t) {
  float e0 = __builtin_amdgcn_exp2f(t.x);
  float e1 = __builtin_amdgcn_exp2f(t.y);
  v2f y = {1.0f + e0, 1.0f + e1};
  float r = frcp(y.x * y.y);
  return (v2f){r * y.y, r * y.x};
}

// Fused setup: [0,N/4) coord | [N/4,N/2) sdf | then keysT | then B | then scale
__global__ __launch_bounds__(256) void k_setup(
    const float* __restrict__ coords, const float* __restrict__ W1,
    const float* __restrict__ b1, const float* __restrict__ W2,
    const float* __restrict__ b2, const float* __restrict__ keys,
    const float* __restrict__ rpos, const float* __restrict__ rrad,
    const float* __restrict__ mem, const float* __restrict__ Wg1,
    const float* __restrict__ Wu1, const float* __restrict__ Wg2,
    float* __restrict__ qe, float* __restrict__ keysT,
    float* __restrict__ sg_out, float* __restrict__ BgT,
    float* __restrict__ Bu, float* __restrict__ wg1r_n,
    float* __restrict__ wu1r_n, float* __restrict__ w2n, int N, int M, int R) {
  int bx = blockIdx.x;
  int NB4 = N / 4;
  if (bx < NB4) {
    // coord_proj: 4 n per block
    int sub = threadIdx.x >> 6, k = threadIdx.x & 63;
    int n = bx * 4 + sub;
    __shared__ float h[4][DD];
    float px = coords[n * 3 + 0], py = coords[n * 3 + 1], pz = coords[n * 3 + 2];
    float t = px * W1[k] + py * W1[DD + k] + pz * W1[2 * DD + k] + b1[k];
    h[sub][k] = fsilu(t);
    __syncthreads();
    float q = b2[k];
#pragma unroll 8
    for (int j = 0; j < DD; j++) q += h[sub][j] * W2[j * DD + k];
    qe[(size_t)n * DD + k] = q;
  } else if (bx < 2 * NB4) {
    // sdf: one wave per n
    int wv = threadIdx.x >> 6, ln = threadIdx.x & 63;
    int n = (bx - NB4) * 4 + wv;
    float px = coords[n * 3], py = coords[n * 3 + 1], pz = coords[n * 3 + 2];
    float mn = 1e30f;
    for (int r = ln; r < R; r += 64) {
      float dx = px - rpos[r * 3], dy = py - rpos[r * 3 + 1],
            dz = pz - rpos[r * 3 + 2];
      float d = sqrtf(dx * dx + dy * dy + dz * dz) - rrad[r];
      mn = fminf(mn, d);
    }
    mn = fminf(mn, __shfl_xor(mn, 32, 64));
    mn = fminf(mn, __shfl_xor(mn, 16, 64));
    mn = fminf(mn, __shfl_xor(mn, 8, 64));
    mn = fminf(mn, __shfl_xor(mn, 4, 64));
    mn = fminf(mn, __shfl_xor(mn, 2, 64));
    mn = fminf(mn, __shfl_xor(mn, 1, 64));
    if (ln == 0) sg_out[n] = fsig(4.0f * mn);
  } else if (bx < 2 * NB4 + DD) {
    // keysT[j][m] = keys[m][j]
    int j = bx - 2 * NB4;
    int t = threadIdx.x;
    keysT[j * M + t] = keys[t * DD + j];
  } else if (bx < 2 * NB4 + DD + M) {
    // initial BgT/Bu (negated log2 domain)
    int m = bx - (2 * NB4 + DD);
    int t = threadIdx.x;
    __shared__ float row[DD];
    if (t < DD) row[t] = mem[m * DD + t];
    __syncthreads();
    if (t < 128) {
      int k = t & 63;
      const float* W = (t < DD) ? Wg1 : Wu1;
      float b = 0.f;
#pragma unroll 8
      for (int j = 0; j < DD; j++) b += row[j] * W[(DD + j) * DD + k];
      b *= NEG_L2E;
      if (t < DD) BgT[k * M + m] = b;
      else Bu[m * DD + k] = b;
    }
  } else {
    // prescaled weight rows
    int k = threadIdx.x;
    if (k < DD) {
      wg1r_n[k] = Wg1[128 * DD + k] * NEG_L2E;
      wu1r_n[k] = Wu1[128 * DD + k] * NEG_L2E;
      w2n[k] = -Wg2[k] * LN2;
    }
  }
}

// 4 n's per block; XCD-aligned with k_write consumers. A-proj outputs in
// negated-log2 domain (x NEG_L2E). No max-sub softmax (logits bounded).
// final==0: skip pure-output stores (rw_out, mc_out).
__global__ __launch_bounds__(256) void k_attn(
    const float* __restrict__ qe_in, const float* __restrict__ keysT,
    const float* __restrict__ mem, const float* __restrict__ sg,
    const float* __restrict__ Wg1, const float* __restrict__ bg1,
    const float* __restrict__ Wu1, const float* __restrict__ bu1,
    float* __restrict__ rw_out, float* __restrict__ rwT,
    float* __restrict__ mc_out, float* __restrict__ qe_io,
    float* __restrict__ AgT4, float* __restrict__ Au, int N, int M, int NCH2,
    int final_step) {
  int bx = blockIdx.x;
  int c = bx % NCH2;        // XCD = bx%8 = c%8
  int j2 = bx / NCH2;       // 0..31
  int n0 = c * 128 + j2 * 4;
  int t = threadIdx.x;  // t == m, M == 256
  int wv = t >> 6, ln = t & 63;
  __shared__ __align__(16) float rws[4][256];
  __shared__ __align__(16) float mcs[4][DD];
  __shared__ float red2[4][4];
  __shared__ float part[4][4][DD];
  float lg[4] = {0.f, 0.f, 0.f, 0.f};
#pragma unroll 8
  for (int j = 0; j < DD; j++) {
    float kv = keysT[j * M + t];
    lg[0] += qe_in[(size_t)(n0 + 0) * DD + j] * kv;  // uniform -> s_load
    lg[1] += qe_in[(size_t)(n0 + 1) * DD + j] * kv;
    lg[2] += qe_in[(size_t)(n0 + 2) * DD + j] * kv;
    lg[3] += qe_in[(size_t)(n0 + 3) * DD + j] * kv;
  }
  float e[4];
#pragma unroll
  for (int q = 0; q < 4; q++) {
    // logits bounded (|logit| < ~10): no max-subtraction needed
    float ee = __expf(lg[q] * 0.125f);
    e[q] = ee;
    float sm = ee;
    sm += __shfl_xor(sm, 32, 64);
    sm += __shfl_xor(sm, 16, 64);
    sm += __shfl_xor(sm, 8, 64);
    sm += __shfl_xor(sm, 4, 64);
    sm += __shfl_xor(sm, 2, 64);
    sm += __shfl_xor(sm, 1, 64);
    if (ln == 0) red2[q][wv] = sm;
  }
  __syncthreads();
  float rv4[4];
#pragma unroll
  for (int q = 0; q < 4; q++) {
    float tot = red2[q][0] + red2[q][1] + red2[q][2] + red2[q][3];
    float rv = e[q] * frcp(tot);
    if (final_step) rw_out[(size_t)(n0 + q) * M + t] = rv;
    rws[q][t] = rv;
    rv4[q] = rv;
  }
  *reinterpret_cast<float4*>(&rwT[(size_t)t * N + n0]) =
      make_float4(rv4[0], rv4[1], rv4[2], rv4[3]);
  __syncthreads();
  float acc[4] = {0.f, 0.f, 0.f, 0.f};
#pragma unroll
  for (int mm4 = 0; mm4 < 16; mm4++) {
    int mbase = wv * 64 + mm4 * 4;
    const float4 r0 = *reinterpret_cast<const float4*>(&rws[0][mbase]);
    const float4 r1 = *reinterpret_cast<const float4*>(&rws[1][mbase]);
    const float4 r2 = *reinterpret_cast<const float4*>(&rws[2][mbase]);
    const float4 r3 = *reinterpret_cast<const float4*>(&rws[3][mbase]);
    float m0v = mem[(size_t)(mbase + 0) * DD + ln];
    float m1v = mem[(size_t)(mbase + 1) * DD + ln];
    float m2v = mem[(size_t)(mbase + 2) * DD + ln];
    float m3v = mem[(size_t)(mbase + 3) * DD + ln];
    acc[0] += r0.x * m0v + r0.y * m1v + r0.z * m2v + r0.w * m3v;
    acc[1] += r1.x * m0v + r1.y * m1v + r1.z * m2v + r1.w * m3v;
    acc[2] += r2.x * m0v + r2.y * m1v + r2.z * m2v + r2.w * m3v;
    acc[3] += r3.x * m0v + r3.y * m1v + r3.z * m2v + r3.w * m3v;
  }
#pragma unroll
  for (int q = 0; q < 4; q++) part[q][wv][ln] = acc[q];
  __syncthreads();
  {
    int q = wv;
    float mc = part[q][0][ln] + part[q][1][ln] + part[q][2][ln] + part[q][3][ln];
    if (final_step) mc_out[(size_t)(n0 + q) * DD + ln] = mc;
    qe_io[(size_t)(n0 + q) * DD + ln] =
        qe_in[(size_t)(n0 + q) * DD + ln] + 0.5f * mc;
    mcs[q][ln] = mc;
  }
  __syncthreads();
  {
    const float* W = (wv < 2) ? Wg1 : Wu1;
    const float* bb = (wv < 2) ? bg1 : bu1;
    int qa = (wv & 1) * 2, qb = qa + 1;
    int k = ln;
    float w129 = W[129 * DD + k];
    float bbk = bb[k];
    float a0 = bbk + sg[n0 + qa] * w129;
    float a1 = bbk + sg[n0 + qb] * w129;
#pragma unroll
    for (int j4 = 0; j4 < 16; j4++) {
      const float4 ma = *reinterpret_cast<const float4*>(&mcs[qa][j4 * 4]);
      const float4 mb = *reinterpret_cast<const float4*>(&mcs[qb][j4 * 4]);
      float w0 = W[(size_t)(j4 * 4 + 0) * DD + k];
      float w1 = W[(size_t)(j4 * 4 + 1) * DD + k];
      float w2v = W[(size_t)(j4 * 4 + 2) * DD + k];
      float w3 = W[(size_t)(j4 * 4 + 3) * DD + k];
      a0 += ma.x * w0 + ma.y * w1 + ma.z * w2v + ma.w * w3;
      a1 += mb.x * w0 + mb.y * w1 + mb.z * w2v + mb.w * w3;
    }
    a0 *= NEG_L2E;
    a1 *= NEG_L2E;
    if (wv < 2) {
      AgT4[((size_t)(k >> 2) * N + n0 + qa) * 4 + (k & 3)] = a0;
      AgT4[((size_t)(k >> 2) * N + n0 + qb) * 4 + (k & 3)] = a1;
    } else {
      Au[(size_t)(n0 + qa) * DD + k] = a0;
      Au[(size_t)(n0 + qb) * DD + k] = a1;
    }
  }
}

// Main pair loop (R13/R17 structure) with packed-fp32 mi-pairs + paired rcp.
// 128 thr = 2 waves over ONE 64-n chunk; wave 0 = gate, wave 1 = delta.
__global__ __launch_bounds__(128) void k_write(
    const float* __restrict__ rwT, const float* __restrict__ AgT4,
    const float* __restrict__ Au, const float* __restrict__ BgT,
    const float* __restrict__ Bu, const float* __restrict__ wg1r_n,
    const float* __restrict__ wu1r_n, const float* __restrict__ w2n,
    const float* __restrict__ bg2, float* __restrict__ gate_part,
    float* __restrict__ su_part, int N, int M, int NCH2) {
  int bx = blockIdx.x;
  int c128 = bx % NCH2;
  int rest = bx / NCH2;
  int half = rest & 1;
  int m0 = (rest >> 1) * 4;
  int NCH4 = NCH2 * 2;
  int c64 = c128 * 2 + half;
  int wave = threadIdx.x >> 6, lane = threadIdx.x & 63;
  int n0 = __builtin_amdgcn_readfirstlane(c64 * 64);

  if (wave == 0) {
    // ---- gate path: lane = n offset, loop k (pipelined ag4) ----
    v2f rwl01, rwl23;
    rwl01.x = rwT[(size_t)(m0 + 0) * N + n0 + lane];
    rwl01.y = rwT[(size_t)(m0 + 1) * N + n0 + lane];
    rwl23.x = rwT[(size_t)(m0 + 2) * N + n0 + lane];
    rwl23.y = rwT[(size_t)(m0 + 3) * N + n0 + lane];
    v2f gacc01 = {0.f, 0.f}, gacc23 = {0.f, 0.f};
    const float* agp = &AgT4[(size_t)(n0 + lane) * 4];
    float4 ag_cur = *reinterpret_cast<const float4*>(agp);
#pragma unroll
    for (int k4 = 0; k4 < 16; k4++) {
      float4 ag_next = (k4 < 15)
          ? *reinterpret_cast<const float4*>(agp + (size_t)(k4 + 1) * N * 4)
          : ag_cur;
      float agv[4] = {ag_cur.x, ag_cur.y, ag_cur.z, ag_cur.w};
#pragma unroll
      for (int kk = 0; kk < 4; kk++) {
        int k = k4 * 4 + kk;
        const float4 bg4 =
            *reinterpret_cast<const float4*>(&BgT[k * M + m0]);  // s_load
        float wr = wg1r_n[k];
        float w2 = w2n[k];
        v2f base01 = {agv[kk] + bg4.x, agv[kk] + bg4.y};
        v2f base23 = {agv[kk] + bg4.z, agv[kk] + bg4.w};
        v2f tp01 = rwl01 * wr + base01;   // pk_fma
        v2f tp23 = rwl23 * wr + base23;   // pk_fma
        v2f s01 = sig_pair(tp01);
        v2f s23 = sig_pair(tp23);
        gacc01 += (tp01 * w2) * s01;      // pk_mul + pk_fma
        gacc23 += (tp23 * w2) * s23;
      }
      ag_cur = ag_next;
    }
    float bg2v = bg2[0];
    float gaccs[4] = {gacc01.x, gacc01.y, gacc23.x, gacc23.y};
    float g[4];
#pragma unroll
    for (int mi = 0; mi < 4; mi++) {
      float gg = fsig(gaccs[mi] + bg2v);
      gg += __shfl_xor(gg, 32, 64);
      gg += __shfl_xor(gg, 16, 64);
      gg += __shfl_xor(gg, 8, 64);
      gg += __shfl_xor(gg, 4, 64);
      gg += __shfl_xor(gg, 2, 64);
      gg += __shfl_xor(gg, 1, 64);
      g[mi] = gg;
    }
    if (lane == 0) {
#pragma unroll
      for (int mi = 0; mi < 4; mi++)
        gate_part[(m0 + mi) * NCH4 + c64] = g[mi];
    }
  } else {
    // ---- delta path: lane = k, loop n (pipelined au) ----
    v2f bu01, bu23;
    bu01.x = Bu[(size_t)(m0 + 0) * DD + lane];
    bu01.y = Bu[(size_t)(m0 + 1) * DD + lane];
    bu23.x = Bu[(size_t)(m0 + 2) * DD + lane];
    bu23.y = Bu[(size_t)(m0 + 3) * DD + lane];
    float wu = wu1r_n[lane];
    v2f su01 = {0.f, 0.f}, su23 = {0.f, 0.f};
    const float* Aup = Au + (size_t)n0 * DD + lane;
    const float* r0p = rwT + (size_t)(m0 + 0) * N + n0;  // contiguous s_loads
    const float* r1p = rwT + (size_t)(m0 + 1) * N + n0;
    const float* r2p = rwT + (size_t)(m0 + 2) * N + n0;
    const float* r3p = rwT + (size_t)(m0 + 3) * N + n0;
    float au_cur = Aup[0];
#pragma unroll 8
    for (int i = 0; i < 64; i++) {
      float au_next = (i < 63) ? Aup[(size_t)(i + 1) * DD] : au_cur;
      v2f rv01 = {r0p[i], r1p[i]};
      v2f rv23 = {r2p[i], r3p[i]};
      v2f base01 = {au_cur + bu01.x, au_cur + bu01.y};
      v2f base23 = {au_cur + bu23.x, au_cur + bu23.y};
      v2f tp01 = rv01 * wu + base01;      // pk_fma
      v2f tp23 = rv23 * wu + base23;      // pk_fma
      v2f s01 = sig_pair(tp01);
      v2f s23 = sig_pair(tp23);
      su01 += tp01 * s01;                 // pk_fma
      su23 += tp23 * s23;
      au_cur = au_next;
    }
    float sus[4] = {su01.x, su01.y, su23.x, su23.y};
#pragma unroll
    for (int mi = 0; mi < 4; mi++)
      su_part[((size_t)(m0 + mi) * NCH4 + c64) * DD + lane] = sus[mi] * (-LN2);
  }
}

// per-m reduce over NCH4=64 chunks, PARALLELIZED: 256 thr; 4 waves split the
// su gather; gate gather is lane-parallel + butterfly.
__global__ __launch_bounds__(256) void k_reduce_b(
    const float* __restrict__ gate_part, const float* __restrict__ su_part,
    const float* __restrict__ Wu2, const float* __restrict__ bu2,
    const float* __restrict__ mem_in, const float* __restrict__ Wg1,
    const float* __restrict__ Wu1, float* __restrict__ mem_out,
    float* __restrict__ gate_out, float* __restrict__ BgT,
    float* __restrict__ Bu, int N, int M, int NCH4) {
  int m = blockIdx.x;
  int t = threadIdx.x;
  int w = t >> 6, k = t & 63;
  __shared__ float su_s4[4][DD];
  __shared__ float su_s[DD];
  __shared__ float row[DD];
  __shared__ float gmean;
  float invN = frcp((float)N);  // N pow2 -> exact
  // su gather: wave w covers chunks c = w, w+4, ...
  float s = 0.f;
  for (int c = w; c < NCH4; c += 4)
    s += su_part[((size_t)m * NCH4 + c) * DD + k];
  su_s4[w][k] = s;
  // gate gather: wave 0, lane = chunk (NCH4 == 64)
  if (w == 0) {
    float g = gate_part[m * NCH4 + k];
    g += __shfl_xor(g, 32, 64);
    g += __shfl_xor(g, 16, 64);
    g += __shfl_xor(g, 8, 64);
    g += __shfl_xor(g, 4, 64);
    g += __shfl_xor(g, 2, 64);
    g += __shfl_xor(g, 1, 64);
    if (k == 0) gmean = g * invN;
  }
  __syncthreads();
  if (t < DD) {
    su_s[k] = (su_s4[0][k] + su_s4[1][k] + su_s4[2][k] + su_s4[3][k]) * invN;
  }
  __syncthreads();
  if (t < DD) {
    float delta = bu2[k];
#pragma unroll 8
    for (int j = 0; j < DD; j++) delta += su_s[j] * Wu2[j * DD + k];
    float v = mem_in[m * DD + k] + gmean * delta;
    mem_out[m * DD + k] = v;
    row[k] = v;
    if (k == 0) gate_out[m] = gmean;
  }
  __syncthreads();
  if (t < 128) {
    const float* W = (t < DD) ? Wg1 : Wu1;
    float b = 0.f;
#pragma unroll 8
    for (int j = 0; j < DD; j++) b += row[j] * W[(DD + j) * DD + k];
    b *= NEG_L2E;
    if (t < DD) BgT[k * M + m] = b;
    else Bu[m * DD + k] = b;
  }
}

extern "C" void kernel_launch(void* const* d_in, const int* in_sizes, int n_in,
                              void* d_out, int out_size, void* d_ws, size_t ws_size,
                              hipStream_t stream) {
  const float* coords = (const float*)d_in[0];
  const float* memory_slots = (const float*)d_in[1];
  const float* anchor_keys = (const float*)d_in[2];
  const float* rpos = (const float*)d_in[3];
  const float* rrad = (const float*)d_in[4];
  const float* W1 = (const float*)d_in[5];
  const float* b1 = (const float*)d_in[6];
  const float* W2 = (const float*)d_in[7];
  const float* b2 = (const float*)d_in[8];
  const float* Wg1 = (const float*)d_in[9];
  const float* bg1 = (const float*)d_in[10];
  const float* Wg2 = (const float*)d_in[11];
  const float* bg2 = (const float*)d_in[12];
  const float* Wu1 = (const float*)d_in[13];
  const float* bu1 = (const float*)d_in[14];
  const float* Wu2 = (const float*)d_in[15];
  const float* bu2 = (const float*)d_in[16];

  const int N = in_sizes[0] / 3;   // 4096
  const int M = in_sizes[1] / DD;  // 256
  const int R = in_sizes[4];       // 512
  const int NCH2 = N / 128;        // 32
  const int NCH4 = N / 64;         // 64

  // d_out layout: mc[N*D] | rw[N*M] | gate[M] | sg[N] | mem[M*D]
  float* out = (float*)d_out;
  float* out_mc = out;
  float* out_rw = out_mc + (size_t)N * DD;
  float* out_gate = out_rw + (size_t)N * M;
  float* out_sg = out_gate + M;
  float* out_mem = out_sg + N;

  // workspace layout (~11.3 MB)
  float* ws = (float*)d_ws;
  float* qe = ws;        ws += (size_t)N * DD;
  float* AgT4 = ws;      ws += (size_t)N * DD;
  float* Au = ws;        ws += (size_t)N * DD;
  float* rwT = ws;       ws += (size_t)M * N;
  float* keysT = ws;     ws += (size_t)DD * M;
  float* BgT = ws;       ws += (size_t)DD * M;
  float* Bu = ws;        ws += (size_t)M * DD;
  float* wg1r_n = ws;    ws += DD;
  float* wu1r_n = ws;    ws += DD;
  float* w2n = ws;       ws += DD;
  float* gate_part = ws; ws += (size_t)M * NCH4;
  float* su_part = ws;   ws += (size_t)M * NCH4 * DD;

  int setup_blocks = (N / 4) * 2 + DD + M + 1;  // coord + sdf + prep + b + scale
  k_setup<<<setup_blocks, 256, 0, stream>>>(
      coords, W1, b1, W2, b2, anchor_keys, rpos, rrad, memory_slots, Wg1, Wu1,
      Wg2, qe, keysT, out_sg, BgT, Bu, wg1r_n, wu1r_n, w2n, N, M, R);

  const float* mem_cur = memory_slots;
  for (int step = 0; step < 2; step++) {
    k_attn<<<N / 4, 256, 0, stream>>>(qe, keysT, mem_cur, out_sg, Wg1, bg1, Wu1,
                                      bu1, out_rw, rwT, out_mc, qe, AgT4, Au,
                                      N, M, NCH2, step == 1 ? 1 : 0);
    k_write<<<(M / 4) * 2 * NCH2, 128, 0, stream>>>(
        rwT, AgT4, Au, BgT, Bu, wg1r_n, wu1r_n, w2n, bg2, gate_part, su_part,
        N, M, NCH2);
    k_reduce_b<<<M, 256, 0, stream>>>(gate_part, su_part, Wu2, bu2, mem_cur,
                                      Wg1, Wu1, out_mem, out_gate, BgT, Bu,
                                      N, M, NCH4);
    mem_cur = out_mem;
  }
}